// Round 5
// baseline (76.615 us; speedup 1.0000x reference)
//
#include <hip/hip_runtime.h>
#include <hip/hip_bf16.h>

#define B_DIM 256
#define NTOK (256 * 512)
#define W1_LD 517
#define TPB 32  // tokens per k_token block

// workspace float offsets
#define WS_DIT 0
#define WS_E 256             // holds 2*e
#define WS_C0 512
#define WS_WX4A 576          // [128] float4 {w512,w513,w514,w515}
#define WS_WX4B 1088         // [128] float4 {w516,b1,w2,0}
#define WS_W1F 2048          // bf16 frag-ordered [8 nblk][16 ks][64 lane][8]
#define WS_SCORE 34816       // [NTOK]

typedef __attribute__((ext_vector_type(8))) short bf16x8;
typedef __attribute__((ext_vector_type(4))) float f32x4;

__device__ __forceinline__ unsigned pk2(float a, float b) {
  __hip_bfloat162 h = __float22bfloat162_rn(make_float2(a, b));
  unsigned r;
  __builtin_memcpy(&r, &h, 4);
  return r;
}

// DPP cross-lane add (VALU pipe — avoids the shared per-CU DS pipe).
template <int CTRL>
__device__ __forceinline__ float dpp_add(float v) {
  int s = __builtin_amdgcn_update_dpp(0, __float_as_int(v), CTRL, 0xf, 0xf,
                                      true);
  return v + __int_as_float(s);
}
// sum over each group of 16 consecutive lanes (DPP row)
__device__ __forceinline__ float row16_sum(float v) {
  v = dpp_add<0xB1>(v);   // quad_perm [1,0,3,2]  (xor 1)
  v = dpp_add<0x4E>(v);   // quad_perm [2,3,0,1]  (xor 2)
  v = dpp_add<0x124>(v);  // row_ror:4
  v = dpp_add<0x128>(v);  // row_ror:8
  return v;
}

__device__ __forceinline__ float wave_sum(float v) {
#pragma unroll
  for (int off = 32; off > 0; off >>= 1) v += __shfl_xor(v, off, 64);
  return v;
}
__device__ __forceinline__ float wave_max(float v) {
#pragma unroll
  for (int off = 32; off > 0; off >>= 1) v = fmaxf(v, __shfl_xor(v, off, 64));
  return v;
}
__device__ __forceinline__ float block_sum(float v, float* scr) {
  v = wave_sum(v);
  int wid = threadIdx.x >> 6;
  __syncthreads();
  if ((threadIdx.x & 63) == 0) scr[wid] = v;
  __syncthreads();
  return scr[0] + scr[1] + scr[2] + scr[3];
}
__device__ __forceinline__ float block_max(float v, float* scr) {
  v = wave_max(v);
  int wid = threadIdx.x >> 6;
  __syncthreads();
  if ((threadIdx.x & 63) == 0) scr[wid] = v;
  __syncthreads();
  return fmaxf(fmaxf(scr[0], scr[1]), fmaxf(scr[2], scr[3]));
}

// ---------------------------------------------------------------------------
// Setup (grid 128): block h converts W1 row h into fragment-ordered bf16
// W1F[n>>4][k>>5][((k>>3)&3)*16 + (n&15)][k&7]; block 0 also builds per-d
// constants (dit, 2e, C0) and the packed wx float4 tables.
// ---------------------------------------------------------------------------
__global__ __launch_bounds__(256) void k_setup(
    const float* __restrict__ W1, const float* __restrict__ b1,
    const float* __restrict__ W2, const float* __restrict__ mu_c,
    const float* __restrict__ log_tau2, const float* __restrict__ log_prior,
    float* __restrict__ wsc) {
  const int tid = threadIdx.x;
  const int h = blockIdx.x;
  ushort* w1f = (ushort*)(wsc + WS_W1F);
  const float* wr = W1 + h * W1_LD;
  const int k = 2 * tid;
  const unsigned pk = pk2(wr[k], wr[k + 1]);
  const int flat = (h >> 4) * 8192 + (k >> 5) * 512 +
                   (((k >> 3) & 3) * 16 + (h & 15)) * 8 + (k & 7);
  *(unsigned*)(w1f + flat) = pk;

  if (blockIdx.x == 0) {
    __shared__ float scr[4];
    float lt0 = log_tau2[tid], lt1 = log_tau2[256 + tid];
    float mc0 = mu_c[tid], mc1 = mu_c[256 + tid];
    float it0 = __expf(-lt0), it1 = __expf(-lt1);
    wsc[WS_DIT + tid] = it1 - it0;
    wsc[WS_E + tid] = 2.0f * (mc1 * it1 - mc0 * it0);
    float g = mc1 * mc1 * it1 - mc0 * mc0 * it0 + (lt1 - lt0);
    float sg = block_sum(g, scr);
    if (tid == 0) wsc[WS_C0] = (log_prior[1] - log_prior[0]) - 0.5f * sg;
    if (tid < 128) {
      const float* w1r = W1 + tid * W1_LD;
      *(float4*)(wsc + WS_WX4A + 4 * tid) =
          make_float4(w1r[512], w1r[513], w1r[514], w1r[515]);
      *(float4*)(wsc + WS_WX4B + 4 * tid) =
          make_float4(w1r[516], b1[tid], W2[tid], 0.0f);
    }
  }
}

// ---------------------------------------------------------------------------
// Token kernel: 32 tokens/block, 512 threads (8 waves), 4 blocks/CU.
// DS-pipe-minimized: DPP reductions, global-sourced constants, split-K MFMA.
// Phase 1: 16 lanes/token x 2 iters (8 d each); phase-A partials in regs,
//          DPP row16 reduce; bf16 A-tile b128-written to XOR-swizzled LDS.
// Phase 2: MFMA 16x16x32_bf16 split-K: wave w = (kh = w>>2, hblk = w&3):
//          h in [32*hblk, 32*hblk+32), ks in [8*kh, 8*kh+8).
//          Partial accs exchanged via LDS (reusing A-tile space).
// ---------------------------------------------------------------------------
__global__ __launch_bounds__(512, 8) void k_token(
    const float* __restrict__ mu, const float* __restrict__ logvar,
    const float* __restrict__ minutes, const float* __restrict__ b2,
    const float* __restrict__ wsc, float* __restrict__ out_s,
    float* __restrict__ ws_score, float* __restrict__ araw_out) {
  __shared__ __align__(16) ushort A_l[TPB * 512];  // 32KB; reused for exchange
  __shared__ __align__(16) float4 ex4_l[TPB];      // {s, minutes, snr1, snr2}
  __shared__ float ex1_l[TPB];                     // {snr3}
  __shared__ float red2[4][TPB];

  const int tid = threadIdx.x;
  const int w = tid >> 6;
  const int l = tid & 63;
  const int tokbase = blockIdx.x * TPB;
  const float C0 = wsc[WS_C0];

  // ---- phase 1: stream + in-register phase-A partials + A-tile staging ----
  const int trow = tid >> 4;  // this thread's token, 0..31
  const int l16 = tid & 15;   // 16 lanes per token, 8 d each per iter
  const int swz = (trow & 7) << 4;
  char* Ab = (char*)A_l;
  const size_t gbase = (size_t)(tokbase + trow) * 256 + l16 * 8;
  float Ss = 0.f, Sm = 0.f, Sl = 0.f, Sc = 0.f;
#pragma unroll 1
  for (int t = 0; t < 2; ++t) {
    const int d0 = t * 128 + l16 * 8;
    const float4 m0 = *(const float4*)(mu + gbase + t * 128);
    const float4 m1 = *(const float4*)(mu + gbase + t * 128 + 4);
    const float4 v0 = *(const float4*)(logvar + gbase + t * 128);
    const float4 v1 = *(const float4*)(logvar + gbase + t * 128 + 4);
    const float4 dA = *(const float4*)(wsc + WS_DIT + d0);
    const float4 dB = *(const float4*)(wsc + WS_DIT + d0 + 4);
    const float4 eA = *(const float4*)(wsc + WS_E + d0);
    const float4 eB = *(const float4*)(wsc + WS_E + d0 + 4);
#define CHUNK(m, lv, dt, ee)                                              \
  {                                                                       \
    const float va = __expf(lv.x), vb = __expf(lv.y), vc = __expf(lv.z), \
                vd = __expf(lv.w);                                        \
    const float qa = m.x * m.x, qb = m.y * m.y, qc = m.z * m.z,           \
                qd = m.w * m.w;                                           \
    Ss += (va + qa) * dt.x - m.x * ee.x + (vb + qb) * dt.y - m.y * ee.y + \
          (vc + qc) * dt.z - m.z * ee.z + (vd + qd) * dt.w - m.w * ee.w;  \
    Sm += qa + qb + qc + qd;                                              \
    Sl += lv.x + lv.y + lv.z + lv.w;                                      \
    Sc += __fdividef(qa, fmaxf(va, 1e-6f)) +                              \
          __fdividef(qb, fmaxf(vb, 1e-6f)) +                              \
          __fdividef(qc, fmaxf(vc, 1e-6f)) +                              \
          __fdividef(qd, fmaxf(vd, 1e-6f));                               \
  }
    CHUNK(m0, v0, dA, eA);
    CHUNK(m1, v1, dB, eB);
#undef CHUNK
    uint4 um, uv;
    um.x = pk2(m0.x, m0.y); um.y = pk2(m0.z, m0.w);
    um.z = pk2(m1.x, m1.y); um.w = pk2(m1.z, m1.w);
    uv.x = pk2(v0.x, v0.y); uv.y = pk2(v0.z, v0.w);
    uv.z = pk2(v1.x, v1.y); uv.w = pk2(v1.z, v1.w);
    const int off = trow * 1024 + t * 256 + l16 * 16;
    *(uint4*)(Ab + (off ^ swz)) = um;
    *(uint4*)(Ab + ((off + 512) ^ swz)) = uv;
  }
  Ss = row16_sum(Ss);
  Sm = row16_sum(Sm);
  Sl = row16_sum(Sl);
  Sc = row16_sum(Sc);
  if (l16 == 0) {
    const float sval = -0.5f * Ss + C0;
    const float mn = minutes[tokbase + trow];
    ex4_l[trow] =
        make_float4(sval, mn, sqrtf(Sm) * (1.0f / 16.0f), Sl * (1.0f / 256.0f));
    ex1_l[trow] = Sc * (1.0f / 256.0f);
    out_s[tokbase + trow] = sval;
    ws_score[tokbase + trow] = Sc;
  }
  __syncthreads();

  // ---- phase 2: split-K MFMA GEMM h = X * W1^T ----
  const int kh = w >> 2;    // k-half (ks 8*kh .. 8*kh+7)
  const int hblk = w & 3;   // h block of 32
  f32x4 acc00 = {0.f, 0.f, 0.f, 0.f};
  f32x4 acc01 = {0.f, 0.f, 0.f, 0.f};
  f32x4 acc10 = {0.f, 0.f, 0.f, 0.f};
  f32x4 acc11 = {0.f, 0.f, 0.f, 0.f};
  const int m_lane = l & 15;
  const int swzA = (m_lane & 7) << 4;
  const int rowA0 = m_lane * 1024;
  const int rowA1 = rowA0 + 16 * 1024;
  const ushort* w1f = (const ushort*)(wsc + WS_W1F);
  const ushort* bp0 = w1f + (2 * hblk) * 8192 + l * 8;
  const ushort* bp1 = bp0 + 8192;
#pragma unroll 2
  for (int j = 0; j < 8; ++j) {
    const int ks = kh * 8 + j;
    const int kByte = ks * 64 + (l >> 4) * 16;
    bf16x8 a0 = *(const bf16x8*)(Ab + ((rowA0 + kByte) ^ swzA));
    bf16x8 a1 = *(const bf16x8*)(Ab + ((rowA1 + kByte) ^ swzA));
    bf16x8 bq0 = *(const bf16x8*)(bp0 + ks * 512);
    bf16x8 bq1 = *(const bf16x8*)(bp1 + ks * 512);
    acc00 = __builtin_amdgcn_mfma_f32_16x16x32_bf16(a0, bq0, acc00, 0, 0, 0);
    acc01 = __builtin_amdgcn_mfma_f32_16x16x32_bf16(a0, bq1, acc01, 0, 0, 0);
    acc10 = __builtin_amdgcn_mfma_f32_16x16x32_bf16(a1, bq0, acc10, 0, 0, 0);
    acc11 = __builtin_amdgcn_mfma_f32_16x16x32_bf16(a1, bq1, acc11, 0, 0, 0);
  }
  __syncthreads();  // all A-tile reads complete; A_l reusable

  // split-K exchange: wave w owns mf = kh; sends the other m-half to w^4.
  f32x4* xch = (f32x4*)A_l;  // [2 nf][8 wave][64 lane]
  xch[0 * 512 + w * 64 + l] = kh ? acc00 : acc10;
  xch[1 * 512 + w * 64 + l] = kh ? acc01 : acc11;
  __syncthreads();
  const f32x4 fin0 = (kh ? acc10 : acc00) + xch[0 * 512 + (w ^ 4) * 64 + l];
  const f32x4 fin1 = (kh ? acc11 : acc01) + xch[1 * 512 + (w ^ 4) * 64 + l];

  // ---- epilogue: extras + relu + W2 dot; DPP reduce over 16 h-lanes ----
  const int mf = kh;
  const int g = l >> 4;
  const int h0 = 32 * hblk + m_lane;
  const int h1 = h0 + 16;
  const float4 wa0 = *(const float4*)(wsc + WS_WX4A + 4 * h0);
  const float4 wb0 = *(const float4*)(wsc + WS_WX4B + 4 * h0);
  const float4 wa1 = *(const float4*)(wsc + WS_WX4A + 4 * h1);
  const float4 wb1 = *(const float4*)(wsc + WS_WX4B + 4 * h1);
#pragma unroll
  for (int r = 0; r < 4; ++r) {
    const int t_loc = 16 * mf + 4 * g + r;
    const float4 e4 = ex4_l[t_loc];
    const float e1v = ex1_l[t_loc];
    float hp0 = fin0[r] + e4.x * wa0.x + e4.y * wa0.y + e4.z * wa0.z +
                e4.w * wa0.w + e1v * wb0.x + wb0.y;
    float hp1 = fin1[r] + e4.x * wa1.x + e4.y * wa1.y + e4.z * wa1.z +
                e4.w * wa1.w + e1v * wb1.x + wb1.y;
    float cs = fmaxf(hp0, 0.f) * wb0.z + fmaxf(hp1, 0.f) * wb1.z;
    cs = row16_sum(cs);
    if (m_lane == 0) red2[hblk][t_loc] = cs;
  }
  __syncthreads();
  if (tid < TPB) {
    float z =
        red2[0][tid] + red2[1][tid] + red2[2][tid] + red2[3][tid] + b2[0];
    araw_out[tokbase + tid] = 1.0f / (1.0f + __expf(-z));
  }
}

// ---------------------------------------------------------------------------
// Per-batch-row kernel: 256 blocks, 256 threads x 2 tokens.
// a_io holds a_raw on entry (written by k_token), final a on exit.
// ---------------------------------------------------------------------------
__global__ __launch_bounds__(256) void k_row(
    const float* __restrict__ minutes, const float* __restrict__ s_in,
    const float* __restrict__ score_in, float* a_io,
    const float* __restrict__ alpha_logits,
    const float* __restrict__ attn_lambda_logit,
    const float* __restrict__ decay_rate_log, float* __restrict__ out_total) {
  __shared__ float scr[4];
  int row = blockIdx.x;
  int tid = threadIdx.x;
  int base = row * 512;
  float sc0 = score_in[base + tid], sc1 = score_in[base + 256 + tid];
  float sv0 = s_in[base + tid], sv1 = s_in[base + 256 + tid];
  float ar0 = a_io[base + tid], ar1 = a_io[base + 256 + tid];
  float mn0 = minutes[base + tid], mn1 = minutes[base + 256 + tid];

  float msc = block_max(fmaxf(sc0, sc1), scr);
  float mmn = block_max(fmaxf(mn0, mn1), scr);
  float sar = block_sum(ar0 + ar1, scr);
  float e0 = __expf(sc0 - msc), e1 = __expf(sc1 - msc);
  float se = block_sum(e0 + e1, scr);

  float lam = 1.0f / (1.0f + __expf(-attn_lambda_logit[0]));
  float alpha = 1.0f / (1.0f + __expf(-alpha_logits[0]));
  float rate = log1pf(__expf(decay_rate_log[0]));

  float inv_sar = 1.0f / fmaxf(sar, 1e-6f);
  float inv_se = 1.0f / se;
  float a00 = lam * ar0 * inv_sar + (1.0f - lam) * e0 * inv_se;
  float a01 = lam * ar1 * inv_sar + (1.0f - lam) * e1 * inv_se;
  float dh0 = fmaxf(mmn - mn0, 0.0f) * (1.0f / 60.0f);
  float dh1 = fmaxf(mmn - mn1, 0.0f) * (1.0f / 60.0f);
  float w0 = a00 * __expf(-rate * dh0);
  float w1 = a01 * __expf(-rate * dh1);
  float sw = block_sum(w0 + w1, scr);
  float inv_sw = 1.0f / fmaxf(sw, 1e-6f);
  float af0 = w0 * inv_sw, af1 = w1 * inv_sw;
  a_io[base + tid] = af0;
  a_io[base + 256 + tid] = af1;
  float smain = block_sum(af0 * sv0 + af1 * sv1, scr);
  float sg0 = 1.0f / (1.0f + __expf(-sv0));
  float sg1 = 1.0f / (1.0f + __expf(-sv1));
  float p0 = fminf(fmaxf(sg0 * af0, 1e-6f), 1.0f - 1e-6f);
  float p1 = fminf(fmaxf(sg1 * af1, 1e-6f), 1.0f - 1e-6f);
  float slg = block_sum(log1pf(-p0) + log1pf(-p1), scr);
  if (tid == 0) {
    float por = 1.0f - __expf(slg);
    por = fminf(fmaxf(por, 1e-6f), 1.0f - 1e-6f);
    float sor = logf(por) - log1pf(-por);
    out_total[row] = alpha * smain + (1.0f - alpha) * sor;
  }
}

extern "C" void kernel_launch(void* const* d_in, const int* in_sizes, int n_in,
                              void* d_out, int out_size, void* d_ws,
                              size_t ws_size, hipStream_t stream) {
  const float* mu = (const float*)d_in[0];
  const float* logvar = (const float*)d_in[1];
  const float* minutes = (const float*)d_in[2];
  const float* mu_c = (const float*)d_in[3];
  const float* log_tau2 = (const float*)d_in[4];
  const float* log_prior = (const float*)d_in[5];
  const float* W1 = (const float*)d_in[6];
  const float* b1 = (const float*)d_in[7];
  const float* W2 = (const float*)d_in[8];
  const float* b2 = (const float*)d_in[9];
  const float* alpha_logits = (const float*)d_in[10];
  const float* attn_lambda_logit = (const float*)d_in[11];
  const float* decay_rate_log = (const float*)d_in[12];

  float* out = (float*)d_out;
  float* out_total = out;             // [256]
  float* out_s = out + B_DIM;        // [131072]
  float* out_a = out + B_DIM + NTOK; // [131072] — holds a_raw between kernels
  float* wsc = (float*)d_ws;
  float* ws_score = wsc + WS_SCORE;

  k_setup<<<128, 256, 0, stream>>>(W1, b1, W2, mu_c, log_tau2, log_prior, wsc);
  k_token<<<NTOK / TPB, 512, 0, stream>>>(mu, logvar, minutes, b2, wsc, out_s,
                                          ws_score, out_a);
  k_row<<<B_DIM, 256, 0, stream>>>(minutes, out_s, ws_score, out_a,
                                   alpha_logits, attn_lambda_logit,
                                   decay_rate_log, out_total);
}